// Round 5
// baseline (71.825 us; speedup 1.0000x reference)
//
#include <hip/hip_runtime.h>
#include <hip/hip_bf16.h>

#define BN 200
#define KK 32
#define NT 13          // 13 n-tiles of 16 priors = 208 (padded, cf=0 for tail)
#define HH 138
#define WW 138
#define HO 550
#define WO 550
#define NPIX (HH*WW)      // 19044
#define NOUT (HO*WO)      // 302500
#define EPS 1e-6f
#define LOG2E 1.4426950408889634f

#if __has_builtin(__builtin_amdgcn_rcpf)
#define RCP(x) __builtin_amdgcn_rcpf(x)
#else
#define RCP(x) (1.0f/(x))
#endif
#if __has_builtin(__builtin_amdgcn_exp2f)
#define EXP2(x) __builtin_amdgcn_exp2f(x)
#else
#define EXP2(x) exp2f(x)
#endif

typedef __attribute__((ext_vector_type(8))) short short8v;   // 8 bf16 (4 VGPRs)
typedef __attribute__((ext_vector_type(4))) float f32x4;     // MFMA acc

static __device__ inline short f2bf(float x) {
    __hip_bfloat16 h = __float2bfloat16(x);   // RNE
    return *reinterpret_cast<short*>(&h);
}

// ---------------- Kernel 0: one-time prep --------------------------------
// bfrag[b][t][l] : mask * (-LOG2E) in MFMA A-fragment lane order (bf16 x8)
//                  (pre-scaled so MFMA emits -s*log2e = sigmoid exp2 arg)
// p4[b][n]       : (isx', isy', -cx*isx', -cy*isy'), isx' = C/sx, C=sqrt(log2e/2)
// cf[b][n]       : conf (0 for padded priors), float4-readable per 4 priors
__global__ __launch_bounds__(256) void k_prep(
    const float* __restrict__ loc,    // [B,200,4]
    const float* __restrict__ conf,   // [B,200]
    const float* __restrict__ mask,   // [B,200,32]
    short8v* __restrict__ bfrag,      // [8*13*64]
    float4* __restrict__ p4,          // [8*13*16]
    float*  __restrict__ cf,          // [8*13*16]
    int* __restrict__ counter)
{
    const int idx = blockIdx.x * 256 + threadIdx.x;   // over 8*13*64 = 6656
    if (idx == 0) *counter = 0;
    if (idx >= 8 * NT * 64) return;
    const int l  = idx & 63;
    const int bt = idx >> 6;
    const int t  = bt % NT;
    const int b  = bt / NT;
    const int n  = t * 16 + (l & 15);
    const int k0 = (l >> 4) * 8;

    short8v v;
#pragma unroll
    for (int j = 0; j < 8; ++j) v[j] = 0;
    if (n < BN) {
        const float4* src = (const float4*)(mask + ((size_t)b * BN + n) * KK + k0);
        float4 u0 = src[0], u1 = src[1];
        v[0] = f2bf(-LOG2E * u0.x); v[1] = f2bf(-LOG2E * u0.y);
        v[2] = f2bf(-LOG2E * u0.z); v[3] = f2bf(-LOG2E * u0.w);
        v[4] = f2bf(-LOG2E * u1.x); v[5] = f2bf(-LOG2E * u1.y);
        v[6] = f2bf(-LOG2E * u1.z); v[7] = f2bf(-LOG2E * u1.w);
    }
    bfrag[idx] = v;

    if (l < 16) {
        float4 pr = {1.f, 1.f, 0.f, 0.f};
        float  cv = 0.f;
        if (n < BN) {
            const float C = sqrtf(0.5f * LOG2E);
            float4 l4 = ((const float4*)loc)[(size_t)b * BN + n];
            float isx = RCP(l4.z) * C;
            float isy = RCP(l4.w) * C;
            pr.x = isx; pr.y = isy;
            pr.z = -l4.x * isx; pr.w = -l4.y * isy;
            cv = conf[(size_t)b * BN + n];
        }
        p4[bt * 16 + (l & 15)] = pr;
        cf[bt * 16 + (l & 15)] = cv;
    }
}

// ---------------- Kernel 1: MFMA, C = [prior-row][pixel-col] -------------
// block = 256 = 4 waves; each wave owns 16 pixels (cols). Priors reduce
// in-lane over the 4 C-regs and over t; only a 2-step butterfly remains.
__global__ __launch_bounds__(256, 4) void k_finalconf(
    const float* __restrict__ proto,  // [B,138,138,32]
    const short8v* __restrict__ bfrag,
    const float4* __restrict__ p4,
    const float*  __restrict__ cf,
    float* __restrict__ fconf)        // [B,138,138]
{
    const int b    = blockIdx.y;
    const int tid  = threadIdx.x;
    const int wid  = tid >> 6;
    const int lane = tid & 63;

    __shared__ short8v s_bf[NT * 64];   // 13312 B
    __shared__ float4  s_p4[NT * 16];   //  3328 B
    __shared__ float4  s_cf[NT * 4];    //   208 B

    // stage pre-converted per-batch tables (L2-resident) into LDS
    const short8v* gbf = bfrag + (size_t)b * NT * 64;
    for (int i = tid; i < NT * 64; i += 256) s_bf[i] = gbf[i];
    const float4* gp4 = p4 + (size_t)b * NT * 16;
    for (int i = tid; i < NT * 16; i += 256) s_p4[i] = gp4[i];
    const float4* gcf = (const float4*)(cf + (size_t)b * NT * 16);
    for (int i = tid; i < NT * 4; i += 256) s_cf[i] = gcf[i];

    const int mbase = blockIdx.x * 64 + wid * 16;
    const int pixel = mbase + (lane & 15);
    const int pc    = pixel < NPIX ? pixel : NPIX - 1;
    const int h = pc / WW, w = pc - h * WW;
    const float xr = (w + 0.5f) * (1.0f / WW);
    const float yr = (h + 0.5f) * (1.0f / HH);

    // B-fragment (proto): lane l holds proto[pix=col=l&15][k=8*(l>>4)+j]
    const int ka = (lane >> 4) * 8;
    const float4* asrc = (const float4*)(proto + ((size_t)b * NPIX + pc) * KK + ka);
    float4 a0 = asrc[0], a1 = asrc[1];
    short8v pfrag;
    pfrag[0] = f2bf(a0.x); pfrag[1] = f2bf(a0.y); pfrag[2] = f2bf(a0.z); pfrag[3] = f2bf(a0.w);
    pfrag[4] = f2bf(a1.x); pfrag[5] = f2bf(a1.y); pfrag[6] = f2bf(a1.z); pfrag[7] = f2bf(a1.w);

    __syncthreads();

    const int g = lane >> 4;             // prior-row group: rows g*4 .. g*4+3
    float sum1 = 0.f, sum2 = 0.f;

#pragma unroll
    for (int t = 0; t < NT; ++t) {
        short8v mf = s_bf[t * 64 + lane];
        f32x4 c = {0.f, 0.f, 0.f, 0.f};
        // A = mask (rows = priors), B = proto (cols = pixels)
        c = __builtin_amdgcn_mfma_f32_16x16x32_bf16(mf, pfrag, c, 0, 0, 0);
        float4 cfv = s_cf[t * 4 + g];
#pragma unroll
        for (int r = 0; r < 4; ++r) {
            float4 pp = s_p4[t * 16 + g * 4 + r];
            const float ms = c[r];                      // = -s*log2e
            const float dx = fmaf(xr, pp.x, pp.z);
            const float dy = fmaf(yr, pp.y, pp.w);
            const float z  = fmaf(dy, dy, dx * dx);     // gauss exp2 arg (>=0)
            const float u  = EXP2(z);
            const float v  = EXP2(z + ms);
            // mc = cf * sigmoid(s) * 2^-z = cf / (2^z + 2^(z - s*log2e))
            const float mc = ((const float*)&cfv)[r] * RCP(u + v);
            sum1 += mc;
            sum2 = fmaf(mc, mc, sum2);
        }
    }

    // combine the 4 prior-row groups (lanes sharing lane&15)
    sum1 += __shfl_xor(sum1, 16);
    sum2 += __shfl_xor(sum2, 16);
    sum1 += __shfl_xor(sum1, 32);
    sum2 += __shfl_xor(sum2, 32);

    if (lane < 16 && pixel < NPIX)
        fconf[(size_t)b * NPIX + pixel] = 1.0f - sum2 * RCP(sum1 + EPS);
}

// ---------------- Kernel 2: bilinear upsample + weighted variance --------
// + deterministic last-block final reduce (fixed summation order).
__global__ __launch_bounds__(256) void k_variance(
    const float* __restrict__ orig,   // [B,3,550,550]
    const float* __restrict__ fconf,  // [B,138,138]
    float* __restrict__ partial,      // [gridDim.x]
    int* __restrict__ counter,
    float* __restrict__ out)
{
    const int idx = blockIdx.x * 256 + threadIdx.x;
    float local = 0.0f;

    if (idx < NOUT) {
        const int yo = idx / WO;
        const int xo = idx - yo * WO;
        const float scale = 138.0f / 550.0f;
        float fy = (yo + 0.5f) * scale - 0.5f;
        float fx = (xo + 0.5f) * scale - 0.5f;
        float fy0 = floorf(fy), fx0 = floorf(fx);
        float wy = fy - fy0, wx = fx - fx0;
        int y0 = max(0, min(HH - 1, (int)fy0));
        int y1 = max(0, min(HH - 1, (int)fy0 + 1));
        int x0 = max(0, min(WW - 1, (int)fx0));
        int x1 = max(0, min(WW - 1, (int)fx0 + 1));

        float R[8];
        float T = 0.0f;
#pragma unroll
        for (int b = 0; b < 8; ++b) {
            const float* F = fconf + (size_t)b * NPIX;
            float v00 = F[y0 * WW + x0], v01 = F[y0 * WW + x1];
            float v10 = F[y1 * WW + x0], v11 = F[y1 * WW + x1];
            float v0 = v00 + wx * (v01 - v00);
            float v1 = v10 + wx * (v11 - v10);
            R[b] = v0 + wy * (v1 - v0);
            T += R[b];
        }
        const float invT = RCP(T + EPS);

#pragma unroll
        for (int c = 0; c < 3; ++c) {
            float o[8];
            float M = 0.0f;
#pragma unroll
            for (int b = 0; b < 8; ++b) {
                o[b] = orig[((size_t)b * 3 + c) * NOUT + idx];
                M = fmaf(o[b], R[b], M);
            }
            float s = 0.0f;
#pragma unroll
            for (int b = 0; b < 8; ++b) {
                float d = o[b] - M;
                s = fmaf(d * d, R[b], s);
            }
            local += s * invT;
        }
    }

    __shared__ float red[4];
    __shared__ int is_last;
    const int lane = threadIdx.x & 63;
    const int wid  = threadIdx.x >> 6;
#pragma unroll
    for (int off = 32; off > 0; off >>= 1)
        local += __shfl_down(local, off);
    if (lane == 0) red[wid] = local;
    __syncthreads();
    if (threadIdx.x == 0) {
        partial[blockIdx.x] = (red[0] + red[1]) + (red[2] + red[3]);
        __threadfence();
        is_last = (atomicAdd(counter, 1) == (int)gridDim.x - 1);
    }
    __syncthreads();

    if (is_last) {
        __threadfence();   // acquire: see all partial[] writes
        float s = 0.0f;
        for (int i = threadIdx.x; i < (int)gridDim.x; i += 256)
            s += partial[i];
#pragma unroll
        for (int off = 32; off > 0; off >>= 1)
            s += __shfl_down(s, off);
        if (lane == 0) red[wid] = s;
        __syncthreads();
        if (threadIdx.x == 0)
            out[0] = (red[0] + red[1]) + (red[2] + red[3]);
    }
}

extern "C" void kernel_launch(void* const* d_in, const int* in_sizes, int n_in,
                              void* d_out, int out_size, void* d_ws, size_t ws_size,
                              hipStream_t stream) {
    const float* original = (const float*)d_in[0];  // [8,3,550,550]
    const float* loc      = (const float*)d_in[1];  // [8,200,4]
    const float* conf     = (const float*)d_in[2];  // [8,200]
    const float* mask     = (const float*)d_in[3];  // [8,200,32]
    const float* proto    = (const float*)d_in[4];  // [8,138,138,32]
    float* out = (float*)d_out;

    const int nb2 = (NOUT + 255) / 256;             // 1182

    char* ws = (char*)d_ws;
    float*   fconf   = (float*)ws;   ws += (size_t)8 * NPIX * sizeof(float);      // 609408
    float*   partial = (float*)ws;   ws += ((size_t)nb2 * sizeof(float) + 63) & ~63ull;
    int*     counter = (int*)ws;     ws += 64;
    short8v* bfrag   = (short8v*)ws; ws += (size_t)8 * NT * 64 * sizeof(short8v); // 106496
    float4*  p4      = (float4*)ws;  ws += (size_t)8 * NT * 16 * sizeof(float4);  // 26624
    float*   cf      = (float*)ws;

    k_prep<<<(8 * NT * 64 + 255) / 256, 256, 0, stream>>>(loc, conf, mask, bfrag, p4, cf, counter);

    dim3 g1((NPIX + 63) / 64, 8);                   // 298 x 8 blocks, 4 waves each
    k_finalconf<<<g1, 256, 0, stream>>>(proto, bfrag, p4, cf, fconf);

    k_variance<<<nb2, 256, 0, stream>>>(original, fconf, partial, counter, out);
}

// Round 6
// 37.556 us; speedup vs baseline: 1.9125x; 1.9125x over previous
//
#include <hip/hip_runtime.h>
#include <hip/hip_bf16.h>

#define BN 200
#define KK 32
#define NT 13          // 13 n-tiles of 16 priors = 208 (padded, cf=0 for tail)
#define HH 138
#define WW 138
#define HO 550
#define WO 550
#define NPIX (HH*WW)      // 19044
#define NOUT (HO*WO)      // 302500
#define EPS 1e-6f
#define LOG2E 1.4426950408889634f

#if __has_builtin(__builtin_amdgcn_rcpf)
#define RCP(x) __builtin_amdgcn_rcpf(x)
#else
#define RCP(x) (1.0f/(x))
#endif
#if __has_builtin(__builtin_amdgcn_exp2f)
#define EXP2(x) __builtin_amdgcn_exp2f(x)
#else
#define EXP2(x) exp2f(x)
#endif

typedef __attribute__((ext_vector_type(8))) short short8v;   // 8 bf16 (4 VGPRs)
typedef __attribute__((ext_vector_type(4))) float f32x4;     // MFMA acc

static __device__ inline short f2bf(float x) {
    __hip_bfloat16 h = __float2bfloat16(x);   // RNE
    return *reinterpret_cast<short*>(&h);
}

// ---------------- Kernel 0: one-time prep --------------------------------
// bfrag[b][t][l] : mask * (-LOG2E) in MFMA A-fragment lane order (bf16 x8)
// p4[b][n]       : (isx', isy', -cx*isx', -cy*isy'), isx' = C/sx, C=sqrt(log2e/2)
// cf[b][n]       : conf (0 for padded priors)
__global__ __launch_bounds__(256) void k_prep(
    const float* __restrict__ loc,    // [B,200,4]
    const float* __restrict__ conf,   // [B,200]
    const float* __restrict__ mask,   // [B,200,32]
    short8v* __restrict__ bfrag,      // [8*13*64]
    float4* __restrict__ p4,          // [8*13*16]
    float*  __restrict__ cf)          // [8*13*16]
{
    const int idx = blockIdx.x * 256 + threadIdx.x;   // over 8*13*64 = 6656
    if (idx >= 8 * NT * 64) return;
    const int l  = idx & 63;
    const int bt = idx >> 6;
    const int t  = bt % NT;
    const int b  = bt / NT;
    const int n  = t * 16 + (l & 15);
    const int k0 = (l >> 4) * 8;

    short8v v;
#pragma unroll
    for (int j = 0; j < 8; ++j) v[j] = 0;
    if (n < BN) {
        const float4* src = (const float4*)(mask + ((size_t)b * BN + n) * KK + k0);
        float4 u0 = src[0], u1 = src[1];
        v[0] = f2bf(-LOG2E * u0.x); v[1] = f2bf(-LOG2E * u0.y);
        v[2] = f2bf(-LOG2E * u0.z); v[3] = f2bf(-LOG2E * u0.w);
        v[4] = f2bf(-LOG2E * u1.x); v[5] = f2bf(-LOG2E * u1.y);
        v[6] = f2bf(-LOG2E * u1.z); v[7] = f2bf(-LOG2E * u1.w);
    }
    bfrag[idx] = v;

    if (l < 16) {
        float4 pr = {1.f, 1.f, 0.f, 0.f};
        float  cv = 0.f;
        if (n < BN) {
            const float C = sqrtf(0.5f * LOG2E);
            float4 l4 = ((const float4*)loc)[(size_t)b * BN + n];
            float isx = RCP(l4.z) * C;
            float isy = RCP(l4.w) * C;
            pr.x = isx; pr.y = isy;
            pr.z = -l4.x * isx; pr.w = -l4.y * isy;
            cv = conf[(size_t)b * BN + n];
        }
        p4[bt * 16 + (l & 15)] = pr;
        cf[bt * 16 + (l & 15)] = cv;
    }
}

// ---------------- Kernel 1: MFMA, C = [prior-row][pixel-col] -------------
// block = 256 = 4 waves; each wave owns 16 pixels (cols). Priors reduce
// in-lane over the 4 C-regs and over t; only a 2-step butterfly remains.
__global__ __launch_bounds__(256, 4) void k_finalconf(
    const float* __restrict__ proto,  // [B,138,138,32]
    const short8v* __restrict__ bfrag,
    const float4* __restrict__ p4,
    const float*  __restrict__ cf,
    float* __restrict__ fconf)        // [B,138,138]
{
    const int b    = blockIdx.y;
    const int tid  = threadIdx.x;
    const int wid  = tid >> 6;
    const int lane = tid & 63;

    __shared__ short8v s_bf[NT * 64];   // 13312 B
    __shared__ float4  s_p4[NT * 16];   //  3328 B
    __shared__ float4  s_cf[NT * 4];    //   208 B

    // stage pre-converted per-batch tables (L2-resident) into LDS
    const short8v* gbf = bfrag + (size_t)b * NT * 64;
    for (int i = tid; i < NT * 64; i += 256) s_bf[i] = gbf[i];
    const float4* gp4 = p4 + (size_t)b * NT * 16;
    for (int i = tid; i < NT * 16; i += 256) s_p4[i] = gp4[i];
    const float4* gcf = (const float4*)(cf + (size_t)b * NT * 16);
    for (int i = tid; i < NT * 4; i += 256) s_cf[i] = gcf[i];

    const int mbase = blockIdx.x * 64 + wid * 16;
    const int pixel = mbase + (lane & 15);
    const int pc    = pixel < NPIX ? pixel : NPIX - 1;
    const int h = pc / WW, w = pc - h * WW;
    const float xr = (w + 0.5f) * (1.0f / WW);
    const float yr = (h + 0.5f) * (1.0f / HH);

    // B-fragment (proto): lane l holds proto[pix=col=l&15][k=8*(l>>4)+j]
    const int ka = (lane >> 4) * 8;
    const float4* asrc = (const float4*)(proto + ((size_t)b * NPIX + pc) * KK + ka);
    float4 a0 = asrc[0], a1 = asrc[1];
    short8v pfrag;
    pfrag[0] = f2bf(a0.x); pfrag[1] = f2bf(a0.y); pfrag[2] = f2bf(a0.z); pfrag[3] = f2bf(a0.w);
    pfrag[4] = f2bf(a1.x); pfrag[5] = f2bf(a1.y); pfrag[6] = f2bf(a1.z); pfrag[7] = f2bf(a1.w);

    __syncthreads();

    const int g = lane >> 4;             // prior-row group: rows g*4 .. g*4+3
    float sum1 = 0.f, sum2 = 0.f;

#pragma unroll
    for (int t = 0; t < NT; ++t) {
        short8v mf = s_bf[t * 64 + lane];
        f32x4 c = {0.f, 0.f, 0.f, 0.f};
        // A = mask (rows = priors), B = proto (cols = pixels)
        c = __builtin_amdgcn_mfma_f32_16x16x32_bf16(mf, pfrag, c, 0, 0, 0);
        float4 cfv = s_cf[t * 4 + g];
#pragma unroll
        for (int r = 0; r < 4; ++r) {
            float4 pp = s_p4[t * 16 + g * 4 + r];
            const float ms = c[r];                      // = -s*log2e
            const float dx = fmaf(xr, pp.x, pp.z);
            const float dy = fmaf(yr, pp.y, pp.w);
            const float z  = fmaf(dy, dy, dx * dx);     // gauss exp2 arg (>=0)
            const float u  = EXP2(z);
            const float v  = EXP2(z + ms);
            // mc = cf * sigmoid(s) * 2^-z = cf / (2^z + 2^(z - s*log2e))
            const float mc = ((const float*)&cfv)[r] * RCP(u + v);
            sum1 += mc;
            sum2 = fmaf(mc, mc, sum2);
        }
    }

    // combine the 4 prior-row groups (lanes sharing lane&15)
    sum1 += __shfl_xor(sum1, 16);
    sum2 += __shfl_xor(sum2, 16);
    sum1 += __shfl_xor(sum1, 32);
    sum2 += __shfl_xor(sum2, 32);

    if (lane < 16 && pixel < NPIX)
        fconf[(size_t)b * NPIX + pixel] = 1.0f - sum2 * RCP(sum1 + EPS);
}

// ---------------- Kernel 2: bilinear upsample + weighted variance --------
// Pure per-block partials: no atomics, no fences (device-scope fences cost
// ~55us here: buffer_wbl2/inv per block serializes the memory system).
__global__ __launch_bounds__(256) void k_variance(
    const float* __restrict__ orig,   // [B,3,550,550]
    const float* __restrict__ fconf,  // [B,138,138]
    float* __restrict__ partial)      // [gridDim.x]
{
    const int idx = blockIdx.x * 256 + threadIdx.x;
    float local = 0.0f;

    if (idx < NOUT) {
        const int yo = idx / WO;
        const int xo = idx - yo * WO;
        const float scale = 138.0f / 550.0f;
        float fy = (yo + 0.5f) * scale - 0.5f;
        float fx = (xo + 0.5f) * scale - 0.5f;
        float fy0 = floorf(fy), fx0 = floorf(fx);
        float wy = fy - fy0, wx = fx - fx0;
        int y0 = max(0, min(HH - 1, (int)fy0));
        int y1 = max(0, min(HH - 1, (int)fy0 + 1));
        int x0 = max(0, min(WW - 1, (int)fx0));
        int x1 = max(0, min(WW - 1, (int)fx0 + 1));

        float R[8];
        float T = 0.0f;
#pragma unroll
        for (int b = 0; b < 8; ++b) {
            const float* F = fconf + (size_t)b * NPIX;
            float v00 = F[y0 * WW + x0], v01 = F[y0 * WW + x1];
            float v10 = F[y1 * WW + x0], v11 = F[y1 * WW + x1];
            float v0 = v00 + wx * (v01 - v00);
            float v1 = v10 + wx * (v11 - v10);
            R[b] = v0 + wy * (v1 - v0);
            T += R[b];
        }
        const float invT = RCP(T + EPS);

#pragma unroll
        for (int c = 0; c < 3; ++c) {
            float o[8];
            float M = 0.0f;
#pragma unroll
            for (int b = 0; b < 8; ++b) {
                o[b] = orig[((size_t)b * 3 + c) * NOUT + idx];
                M = fmaf(o[b], R[b], M);
            }
            float s = 0.0f;
#pragma unroll
            for (int b = 0; b < 8; ++b) {
                float d = o[b] - M;
                s = fmaf(d * d, R[b], s);
            }
            local += s * invT;
        }
    }

    __shared__ float red[4];
    const int lane = threadIdx.x & 63;
    const int wid  = threadIdx.x >> 6;
#pragma unroll
    for (int off = 32; off > 0; off >>= 1)
        local += __shfl_down(local, off);
    if (lane == 0) red[wid] = local;
    __syncthreads();
    if (threadIdx.x == 0)
        partial[blockIdx.x] = (red[0] + red[1]) + (red[2] + red[3]);
}

// ---------------- Kernel 3: deterministic final reduce -------------------
__global__ __launch_bounds__(256) void k_reduce(
    const float* __restrict__ partial, int n, float* __restrict__ out)
{
    float s = 0.0f;
    for (int i = threadIdx.x; i < n; i += 256) s += partial[i];
    __shared__ float red[4];
    const int lane = threadIdx.x & 63;
    const int wid  = threadIdx.x >> 6;
#pragma unroll
    for (int off = 32; off > 0; off >>= 1)
        s += __shfl_down(s, off);
    if (lane == 0) red[wid] = s;
    __syncthreads();
    if (threadIdx.x == 0)
        out[0] = (red[0] + red[1]) + (red[2] + red[3]);
}

extern "C" void kernel_launch(void* const* d_in, const int* in_sizes, int n_in,
                              void* d_out, int out_size, void* d_ws, size_t ws_size,
                              hipStream_t stream) {
    const float* original = (const float*)d_in[0];  // [8,3,550,550]
    const float* loc      = (const float*)d_in[1];  // [8,200,4]
    const float* conf     = (const float*)d_in[2];  // [8,200]
    const float* mask     = (const float*)d_in[3];  // [8,200,32]
    const float* proto    = (const float*)d_in[4];  // [8,138,138,32]
    float* out = (float*)d_out;

    const int nb2 = (NOUT + 255) / 256;             // 1182

    char* ws = (char*)d_ws;
    float*   fconf   = (float*)ws;   ws += (size_t)8 * NPIX * sizeof(float);      // 609408
    float*   partial = (float*)ws;   ws += ((size_t)nb2 * sizeof(float) + 63) & ~63ull;
    short8v* bfrag   = (short8v*)ws; ws += (size_t)8 * NT * 64 * sizeof(short8v); // 106496
    float4*  p4      = (float4*)ws;  ws += (size_t)8 * NT * 16 * sizeof(float4);  // 26624
    float*   cf      = (float*)ws;

    k_prep<<<(8 * NT * 64 + 255) / 256, 256, 0, stream>>>(loc, conf, mask, bfrag, p4, cf);

    dim3 g1((NPIX + 63) / 64, 8);                   // 298 x 8 blocks, 4 waves each
    k_finalconf<<<g1, 256, 0, stream>>>(proto, bfrag, p4, cf, fconf);

    k_variance<<<nb2, 256, 0, stream>>>(original, fconf, partial);

    k_reduce<<<1, 256, 0, stream>>>(partial, nb2, out);
}